// Round 13
// baseline (217.733 us; speedup 1.0000x reference)
//
#include <hip/hip_runtime.h>
#include <stdint.h>

typedef unsigned short u16;
typedef unsigned int u32;
typedef __bf16 bf16x8 __attribute__((ext_vector_type(8)));
typedef float floatx4 __attribute__((ext_vector_type(4)));
typedef u16 u16x8 __attribute__((ext_vector_type(8)));
typedef u16 u16x4 __attribute__((ext_vector_type(4)));

__device__ __forceinline__ u16 f2bf(float f) {
    __bf16 h = (__bf16)f;
    return __builtin_bit_cast(u16, h);
}

// async global->LDS, 16B per lane. LDS dest = wave-uniform base + lane*16.
__device__ __forceinline__ void gll16(const u16* g, u16* l) {
    typedef __attribute__((address_space(1))) u32 gu32;
    typedef __attribute__((address_space(3))) u32 lu32;
    __builtin_amdgcn_global_load_lds((gu32*)g, (lu32*)l, 16, 0, 0);
}

// ---------------------------------------------------------------------------
// One-shot fp32->bf16 convert of h_q, concat(kv1,kv2), and W_in. (verbatim)
// ---------------------------------------------------------------------------
__global__ __launch_bounds__(256) void cvt_all(const float* __restrict__ hq,
                                               const float* __restrict__ kv1,
                                               const float* __restrict__ kv2,
                                               const float* __restrict__ win,
                                               u16* __restrict__ a_q,
                                               u16* __restrict__ a_kv,
                                               u16* __restrict__ wb) {
    const int NQ = 262144, NKV = 786432, NW = 393216;   // 8-elem chunks
    int i = blockIdx.x * 256 + threadIdx.x;
    const int stride = gridDim.x * 256;
    for (; i < NQ + NKV + NW; i += stride) {
        const float* src; u16* dst;
        if (i < NQ) {
            src = hq + (long long)i * 8; dst = a_q + (long long)i * 8;
        } else if (i < NQ + NKV) {
            int c = i - NQ;
            int row = c >> 7;                 // 128 chunks per 1024-elem row
            int col = (c & 127) * 8;
            int b = row >= 3072, r = row - b * 3072;
            src = (r < 1024) ? kv1 + ((long long)(b * 1024 + r)) * 1024 + col
                             : kv2 + ((long long)(b * 2048 + (r - 1024))) * 1024 + col;
            dst = a_kv + (long long)row * 1024 + col;
        } else {
            int c = i - (NQ + NKV);
            src = win + (long long)c * 8; dst = wb + (long long)c * 8;
        }
        floatx4 x = *(const floatx4*)src;
        floatx4 y = *(const floatx4*)(src + 4);
        u16x8 o;
        #pragma unroll
        for (int j = 0; j < 4; j++) { o[j] = f2bf(x[j]); o[4 + j] = f2bf(y[j]); }
        *(u16x8*)dst = o;
    }
}

// ---------------------------------------------------------------------------
// Fused Q+K+V projection v6: BK=32, TRIPLE-buffered (3 x 16 KB = 48 KB LDS
// -> 3 blocks/CU), ONE barrier per step, 2-step prefetch depth:
//   vmcnt(4) [own stage(t) landed; 4 newer = stage(t+1)]
//   -> s_barrier [cross-wave ready + compute(t-1) done -> WAR for stage(t+2)]
//   -> stage(t+2) -> ds_read + 16 MFMA -> lgkmcnt(0).
// Conflict-free BK=32 layout: chunk' = g ^ ((row>>1)&3) (pre-swizzled source;
// reads hit 8 distinct 4-bank slots per 16 lanes = 2-way, free).
// Epilogue unchanged (Q pre-scaled by 0.125*log2e, V transposed).
// ---------------------------------------------------------------------------
__global__ __launch_bounds__(256) void gemm_proj(const u16* __restrict__ aq,
                                                 const u16* __restrict__ akv,
                                                 const u16* __restrict__ wb,
                                                 const float* __restrict__ bias,
                                                 u16* __restrict__ Qo,
                                                 u16* __restrict__ Ko,
                                                 u16* __restrict__ VTg) {
    __shared__ u16 lds[3][2][4096];    // [buf][A|B][128 rows x 32 cols]
    const int tid = threadIdx.x;
    const int wave = tid >> 6, lane = tid & 63;
    const int lane16 = lane & 15, quad = lane >> 4;
    const int bid = blockIdx.x;
    const int g = (bid & 7) * 112 + (bid >> 3);   // XCD swizzle, 896%8==0
    const bool qblk = g < 128;
    int my, nx;
    if (qblk) { my = g >> 3; nx = g & 7; }            // 16 x 8
    else { int gg = g - 128; my = gg >> 4; nx = gg & 15; }  // 48 x 16
    const int rowBase = my * 128;
    const int colBase = nx * 128;
    const int wrow = (qblk ? 0 : 1024) + colBase;
    const int wm = (wave >> 1) * 64, wn = (wave & 1) * 64;

    floatx4 acc[4][4];
    #pragma unroll
    for (int am = 0; am < 4; am++)
        #pragma unroll
        for (int bn = 0; bn < 4; bn++) acc[am][bn] = floatx4{0.f, 0.f, 0.f, 0.f};

    // staging: thread -> row (tid>>2, +64 on 2nd call), chunk' (tid&3);
    // global chunk g = (tid&3) ^ ((row>>1)&3)  [row>>1 mod 4 == (srow>>1)&3]
    const int srow = tid >> 2;                       // 0..63
    const int sg   = (tid & 3) ^ ((srow >> 1) & 3);
    const u16* aS = (qblk ? aq : akv) + (long long)(rowBase + srow) * 1024 + sg * 8;
    const u16* bS = wb + (long long)(wrow + srow) * 1024 + sg * 8;
    u16* lbase = &lds[0][0][0];
    const int ldst = wave * 512;               // u16; HW adds lane*16 B

#define PSTAGE(T_, BUF_) {                                                   \
        const int k0_ = (T_) * 32;                                           \
        u16* d_ = lbase + (BUF_) * 8192;                                     \
        gll16(aS + k0_,         d_        + ldst);                           \
        gll16(aS + k0_ + 65536, d_ + 2048 + ldst);                           \
        gll16(bS + k0_,         d_ + 4096 + ldst);                           \
        gll16(bS + k0_ + 65536, d_ + 6144 + ldst); }

    PSTAGE(0, 0)
    PSTAGE(1, 1)

    // fragment read chunk: quad ^ ((R>>1)&3) with R = wm/wn + i*16 + lane16;
    // wm/wn/i*16 are multiples of 16 -> (R>>1)&3 == (lane16>>1)&3.
    const int cko = ((quad ^ ((lane16 >> 1) & 3)) * 8);

    int bufc = 0, bufs = 2;                    // compute buf, stage buf
    for (int t = 0; t < 32; t++) {
        if (t + 2 < 32) asm volatile("s_waitcnt vmcnt(4)" ::: "memory");
        else            asm volatile("s_waitcnt vmcnt(0)" ::: "memory");
        __builtin_amdgcn_s_barrier();          // ready(t) + WAR for stage(t+2)
        __builtin_amdgcn_sched_barrier(0);
        if (t + 2 < 32) PSTAGE(t + 2, bufs)
        const u16* Ab = lbase + bufc * 8192;
        const u16* Bb = Ab + 4096;
        u16x8 af[4], bf[4];
        #pragma unroll
        for (int i = 0; i < 4; i++) {
            af[i] = *(const u16x8*)&Ab[(wm + i * 16 + lane16) * 32 + cko];
            bf[i] = *(const u16x8*)&Bb[(wn + i * 16 + lane16) * 32 + cko];
        }
        __builtin_amdgcn_s_setprio(1);
        #pragma unroll
        for (int am = 0; am < 4; am++)
            #pragma unroll
            for (int bn = 0; bn < 4; bn++)
                acc[am][bn] = __builtin_amdgcn_mfma_f32_16x16x32_bf16(
                    __builtin_bit_cast(bf16x8, af[am]),
                    __builtin_bit_cast(bf16x8, bf[bn]), acc[am][bn], 0, 0, 0);
        __builtin_amdgcn_s_setprio(0);
        asm volatile("s_waitcnt lgkmcnt(0)" ::: "memory");
        __builtin_amdgcn_sched_barrier(0);
        bufc = (bufc == 2) ? 0 : bufc + 1;
        bufs = (bufs == 2) ? 0 : bufs + 1;
    }
#undef PSTAGE

    const float* bcol = bias + (qblk ? 0 : 1024) + colBase;
    if (qblk || nx < 8) {                      // Q / K: natural [row][d] bf16
        u16* Cb = qblk ? Qo : Ko;
        #pragma unroll
        for (int am = 0; am < 4; am++)
            #pragma unroll
            for (int bn = 0; bn < 4; bn++)
                #pragma unroll
                for (int r = 0; r < 4; r++) {
                    int row = rowBase + wm + am * 16 + quad * 4 + r;
                    int col = wn + bn * 16 + lane16;
                    float v = acc[am][bn][r] + bcol[col];
                    if (qblk) v *= 0.1803368801f;   // 0.125*log2(e): exp2 domain
                    Cb[(long long)row * 1024 + colBase + col] = f2bf(v);
                }
    } else {                                   // V: transposed vT[b][d][key]
        const int b_ = rowBase >= 3072;
        const int keyBase = rowBase - b_ * 3072 + wm;
        #pragma unroll
        for (int am = 0; am < 4; am++)
            #pragma unroll
            for (int bn = 0; bn < 4; bn++) {
                int col = wn + bn * 16 + lane16;
                int d = colBase - 1024 + col;
                int key0 = keyBase + am * 16 + quad * 4;
                u16x4 pk;
                #pragma unroll
                for (int r = 0; r < 4; r++) pk[r] = f2bf(acc[am][bn][r] + bcol[col]);
                *(u16x4*)&VTg[((long long)(b_ * 1024 + d)) * 3072 + key0] = pk;
            }
    }
}

// ---------------------------------------------------------------------------
// Out-projection (verbatim from passing R12): split-K=4, BK=64, counted-vmcnt
// 2-barrier sync. fp32 partials ao[kh] (8 MB apart); ln sums all 4.
// ---------------------------------------------------------------------------
__global__ __launch_bounds__(256) void gemm_out(const u16* __restrict__ ctx,
                                                const u16* __restrict__ wob,
                                                const float* __restrict__ bias,
                                                float* __restrict__ ao) {
    __shared__ u16 lds[2][2][8192];
    const int tid = threadIdx.x;
    const int wave = tid >> 6, lane = tid & 63;
    const int lane16 = lane & 15, quad = lane >> 4;
    const int bid = blockIdx.x;
    const int g = (bid & 7) * 64 + (bid >> 3);        // 512%8==0
    const int my = g >> 5;                            // 16
    const int r5 = g & 31;
    const int nx = r5 >> 2;                           // 8
    const int kh = r5 & 3;                            // 4
    const int rowBase = my * 128, colBase = nx * 128, kbase = kh * 256;
    const int wm = (wave >> 1) * 64, wn = (wave & 1) * 64;

    floatx4 acc[4][4];
    #pragma unroll
    for (int am = 0; am < 4; am++)
        #pragma unroll
        for (int bn = 0; bn < 4; bn++) acc[am][bn] = floatx4{0.f, 0.f, 0.f, 0.f};

    const int srow8 = tid >> 3;
    const int scol = ((tid & 7) ^ (srow8 & 7)) * 8;
    const u16* aS = ctx + (long long)(rowBase + srow8) * 1024 + kbase + scol;
    const u16* bS = wob + (long long)(colBase + srow8) * 1024 + kbase + scol;
    u16* lbase = &lds[0][0][0];
    const int ldst = wave * 512;
    const int cko0 = ((quad ^ (lane16 & 7)) * 8);
    const int cko1 = (((4 + quad) ^ (lane16 & 7)) * 8);

    {
        u16* dA = lbase; u16* dB = lbase + 8192;
        #pragma unroll
        for (int j = 0; j < 4; j++) {
            gll16(aS + j * 32768, dA + j * 2048 + ldst);
            gll16(bS + j * 32768, dB + j * 2048 + ldst);
        }
    }
    __syncthreads();

    int buf = 0;
    for (int t = 0; t < 4; t++) {
        if (t < 3) {
            const int k0 = (t + 1) * 64;
            u16* dA = lbase + (buf ^ 1) * 16384;
            u16* dB = dA + 8192;
            #pragma unroll
            for (int j = 0; j < 4; j++) {
                gll16(aS + j * 32768 + k0, dA + j * 2048 + ldst);
                gll16(bS + j * 32768 + k0, dB + j * 2048 + ldst);
            }
            asm volatile("s_waitcnt vmcnt(8)" ::: "memory");
        } else {
            asm volatile("s_waitcnt vmcnt(0)" ::: "memory");
        }
        __builtin_amdgcn_s_barrier();          // DATA-READY barrier
        __builtin_amdgcn_sched_barrier(0);
        const u16* Ab = lbase + buf * 16384;
        const u16* Bb = Ab + 8192;
        u16x8 a0[4], a1[4], b0[4], b1[4];
        #pragma unroll
        for (int i = 0; i < 4; i++) {
            a0[i] = *(const u16x8*)&Ab[(wm + i * 16 + lane16) * 64 + cko0];
            a1[i] = *(const u16x8*)&Ab[(wm + i * 16 + lane16) * 64 + cko1];
            b0[i] = *(const u16x8*)&Bb[(wn + i * 16 + lane16) * 64 + cko0];
            b1[i] = *(const u16x8*)&Bb[(wn + i * 16 + lane16) * 64 + cko1];
        }
        #pragma unroll
        for (int am = 0; am < 4; am++)
            #pragma unroll
            for (int bn = 0; bn < 4; bn++)
                acc[am][bn] = __builtin_amdgcn_mfma_f32_16x16x32_bf16(
                    __builtin_bit_cast(bf16x8, a0[am]),
                    __builtin_bit_cast(bf16x8, b0[bn]), acc[am][bn], 0, 0, 0);
        #pragma unroll
        for (int am = 0; am < 4; am++)
            #pragma unroll
            for (int bn = 0; bn < 4; bn++)
                acc[am][bn] = __builtin_amdgcn_mfma_f32_16x16x32_bf16(
                    __builtin_bit_cast(bf16x8, a1[am]),
                    __builtin_bit_cast(bf16x8, b1[bn]), acc[am][bn], 0, 0, 0);
        asm volatile("s_waitcnt lgkmcnt(0)" ::: "memory");
        __builtin_amdgcn_s_barrier();          // WAR barrier
        __builtin_amdgcn_sched_barrier(0);
        buf ^= 1;
    }

    float* Co = ao + (long long)kh * 2097152;  // partials 8 MB (2M floats) apart
    #pragma unroll
    for (int am = 0; am < 4; am++)
        #pragma unroll
        for (int bn = 0; bn < 4; bn++)
            #pragma unroll
            for (int r = 0; r < 4; r++) {
                int row = rowBase + wm + am * 16 + quad * 4 + r;
                int col = colBase + wn + bn * 16 + lane16;
                float v = acc[am][bn][r] + (kh == 0 ? bias[col] : 0.f);
                Co[(long long)row * 1024 + col] = v;
            }
}

// ---------------------------------------------------------------------------
// MFMA flash attention v6 (verbatim from passing R12): race-fixed counted-
// vmcnt pipeline, longest-first dispatch, l via ones-MFMA, exp2, defer-max.
// ---------------------------------------------------------------------------
#define ATTN_TILE(DIAG_, HAVENEXT_)                                           \
{                                                                             \
    const int cur = t & 1;                                                    \
    if (HAVENEXT_) {                                                          \
        const long long ko = (long long)(t + 1) * 65536;                      \
        const long long vo = (long long)(t + 1) * 64;                         \
        _Pragma("unroll")                                                     \
        for (int j = 0; j < 2; j++) {                                         \
            gll16(kS + ko + j * 32768, &Kt[cur ^ 1][j * 2048 + ldst]);        \
            gll16(vS + vo + (long long)j * 32 * 3072, &Vt[cur ^ 1][j * 2048 + ldst]); \
        }                                                                     \
        asm volatile("s_waitcnt vmcnt(4)" ::: "memory");  /* own cur landed */ \
    } else {                                                                  \
        asm volatile("s_waitcnt vmcnt(0)" ::: "memory");                      \
    }                                                                         \
    __builtin_amdgcn_s_barrier();              /* DATA-READY: all waves */    \
    __builtin_amdgcn_sched_barrier(0);                                        \
    floatx4 sacc[4];                                                          \
    _Pragma("unroll")                                                         \
    for (int mi = 0; mi < 4; mi++) sacc[mi] = floatx4{0.f, 0.f, 0.f, 0.f};    \
    __builtin_amdgcn_s_setprio(1);                                            \
    _Pragma("unroll")                                                         \
    for (int mi = 0; mi < 4; mi++) {                                          \
        u16x8 kf = *(const u16x8*)&Kt[cur][(mi * 16 + lane16) * 64 + slot0];  \
        sacc[mi] = __builtin_amdgcn_mfma_f32_16x16x32_bf16(                   \
            __builtin_bit_cast(bf16x8, kf), qf[0], sacc[mi], 0, 0, 0);        \
    }                                                                         \
    _Pragma("unroll")                                                         \
    for (int mi = 0; mi < 4; mi++) {                                          \
        u16x8 kf = *(const u16x8*)&Kt[cur][(mi * 16 + lane16) * 64 + slot1];  \
        sacc[mi] = __builtin_amdgcn_mfma_f32_16x16x32_bf16(                   \
            __builtin_bit_cast(bf16x8, kf), qf[1], sacc[mi], 0, 0, 0);        \
    }                                                                         \
    __builtin_amdgcn_s_setprio(0);                                            \
    if (DIAG_) {                               /* mask only on diagonal tile */ \
        _Pragma("unroll")                                                     \
        for (int mi = 0; mi < 4; mi++)                                        \
            _Pragma("unroll")                                                 \
            for (int r = 0; r < 4; r++)                                       \
                if ((mi * 16 + quad * 4 + r) > qloc) sacc[mi][r] = -1e30f;    \
    }                                                                         \
    float tmax = fmaxf(sacc[0][0], sacc[0][1]);                               \
    tmax = fmaxf(tmax, fmaxf(sacc[0][2], sacc[0][3]));                        \
    _Pragma("unroll")                                                         \
    for (int mi = 1; mi < 4; mi++) {                                          \
        tmax = fmaxf(tmax, fmaxf(sacc[mi][0], sacc[mi][1]));                  \
        tmax = fmaxf(tmax, fmaxf(sacc[mi][2], sacc[mi][3]));                  \
    }                                                                         \
    if (!__all(tmax <= m_i + 8.0f)) {          /* rescale only on big jump */ \
        float tr = fmaxf(tmax, __shfl_xor(tmax, 16));                         \
        tr = fmaxf(tr, __shfl_xor(tr, 32));                                   \
        float m_new = fmaxf(m_i, tr);                                         \
        float alpha = exp2f(m_i - m_new);                                     \
        _Pragma("unroll")                                                     \
        for (int mi = 0; mi < 4; mi++)                                        \
            _Pragma("unroll")                                                 \
            for (int r = 0; r < 4; r++) o_acc[mi][r] *= alpha;                \
        l_acc[0] *= alpha;                     /* only [0] is ever read */    \
        m_i = m_new;                                                          \
    }                                                                         \
    _Pragma("unroll")                                                         \
    for (int mi = 0; mi < 4; mi++) {                                          \
        u16x4 pk;                                                             \
        _Pragma("unroll")                                                     \
        for (int r = 0; r < 4; r++) pk[r] = f2bf(exp2f(sacc[mi][r] - m_i));   \
        *(u16x4*)&Ps[wave][lane16 * 64 +                                      \
            (((mi * 2 + (quad >> 1)) ^ (lane16 & 7)) << 3) + (quad & 1) * 4] = pk; \
    }                                                                         \
    __builtin_amdgcn_wave_barrier();                                          \
    __builtin_amdgcn_s_setprio(1);                                            \
    _Pragma("unroll")                                                         \
    for (int c = 0; c < 2; c++) {                                             \
        bf16x8 pf = __builtin_bit_cast(bf16x8, *(const u16x8*)&Ps[wave][      \
            lane16 * 64 + (((c * 4 + quad) ^ (lane16 & 7)) << 3)]);           \
        const int slot = c ? slot1 : slot0;                                   \
        _Pragma("unroll")                                                     \
        for (int mi = 0; mi < 4; mi++) {                                      \
            bf16x8 vf = __builtin_bit_cast(bf16x8,                            \
                *(const u16x8*)&Vt[cur][(mi * 16 + lane16) * 64 + slot]);     \
            o_acc[mi] = __builtin_amdgcn_mfma_f32_16x16x32_bf16(vf, pf, o_acc[mi], 0, 0, 0); \
        }                                                                     \
        l_acc = __builtin_amdgcn_mfma_f32_16x16x32_bf16(onesf, pf, l_acc, 0, 0, 0); \
    }                                                                         \
    __builtin_amdgcn_s_setprio(0);                                            \
    if (HAVENEXT_) {                           /* WAR barrier, NO vmcnt drain */ \
        asm volatile("s_waitcnt lgkmcnt(0)" ::: "memory");                    \
        __builtin_amdgcn_s_barrier();                                         \
        __builtin_amdgcn_sched_barrier(0);                                    \
    }                                                                         \
}

__global__ __launch_bounds__(256) void attn_seg(const u16* __restrict__ Q,
                                                const u16* __restrict__ Kb,
                                                const u16* __restrict__ VTg,
                                                float* __restrict__ pO_lo,
                                                float* __restrict__ pO_hi,
                                                float* __restrict__ pml) {
    __shared__ u16 Kt[2][4096];        // [key 64][d 64], d-chunk XOR-swizzled
    __shared__ u16 Vt[2][4096];        // [d 64][key 64], key-chunk XOR-swizzled
    __shared__ u16 Ps[4][1024];        // per-wave P, stride 64, granule-XOR
    const int tid = threadIdx.x;
    const int wave = tid >> 6, lane = tid & 63;
    const int lane16 = lane & 15, quad = lane >> 4;
    const int bid = blockIdx.x;
    // longest-first: 96 blocks per qt class (2b x 16h x 3seg), qt descending
    const int qrank = bid / 96;                  // 0..15
    const int r_    = bid - qrank * 96;          // 0..95
    const int qt  = 15 - qrank;
    const int b   = r_ / 48;
    const int r2  = r_ - b * 48;
    const int seg = r2 >> 4;
    const int h   = r2 & 15;
    const int l0 = qt * 64;
    const int wq = wave * 16;
    const int qloc = wq + lane16;

    bf16x8 qf[2];
    {
        const u16* qrow = Q + ((long long)(b * 1024 + l0 + wq + lane16)) * 1024 + h * 64;
        qf[0] = __builtin_bit_cast(bf16x8, *(const u16x8*)(qrow + quad * 8));
        qf[1] = __builtin_bit_cast(bf16x8, *(const u16x8*)(qrow + 32 + quad * 8));
    }
    u16x8 onesu;
    #pragma unroll
    for (int j = 0; j < 8; j++) onesu[j] = 0x3F80;       // bf16 1.0
    const bf16x8 onesf = __builtin_bit_cast(bf16x8, onesu);

    const int srow = tid >> 3;                       // 0..31
    const int csw8 = ((tid & 7) ^ (srow & 7)) * 8;
    const long long bh = ((long long)b * 3072) * 1024 + h * 64;
    const u16* kS = Kb + bh + ((long long)(seg * 1024)) * 1024
                    + (long long)srow * 1024 + csw8;             // +t*65536
    const u16* vS = VTg + ((long long)(b * 1024 + h * 64 + srow)) * 3072
                    + seg * 1024 + csw8;                          // +t*64
    const int ldst = wave * 512;                     // u16; HW adds lane*16B

    {   // prologue: tile 0 -> buf 0; full drain ONCE (Q loads + stage)
        #pragma unroll
        for (int j = 0; j < 2; j++) {
            gll16(kS + j * 32768, &Kt[0][j * 2048 + ldst]);
            gll16(vS + (long long)j * 32 * 3072, &Vt[0][j * 2048 + ldst]);
        }
    }
    __syncthreads();

    const int slot0 = ((quad ^ (lane16 & 7)) * 8);
    const int slot1 = (((4 + quad) ^ (lane16 & 7)) * 8);

    float m_i = -1e30f;
    floatx4 o_acc[4];
    floatx4 l_acc = floatx4{0.f, 0.f, 0.f, 0.f};     // row-sum via ones-MFMA
    #pragma unroll
    for (int mi = 0; mi < 4; mi++) o_acc[mi] = floatx4{0.f, 0.f, 0.f, 0.f};

    for (int t = 0; t < qt; t++) ATTN_TILE(false, true)   // full tiles, no mask
    { int t = qt; ATTN_TILE(true, false) }                // diagonal tile

    const float l_i = l_acc[0];    // full key-sum for q=lane16 (rows identical)

    // ---- emit partials (m in log2 domain; combine uses exp2) ----
    const int p = ((b * 16 + h) * 16 + qt) * 3 + seg;     // 0..1535
    float* op = (p < 512) ? (pO_lo + (long long)p * 4096)
                          : (pO_hi + (long long)(p - 512) * 4096);
    if (quad == 0) {
        pml[(long long)p * 128 + (wq + lane16) * 2]     = m_i;
        pml[(long long)p * 128 + (wq + lane16) * 2 + 1] = l_i;
    }
    float* orow = op + (long long)(wq + lane16) * 64;
    #pragma unroll
    for (int mi = 0; mi < 4; mi++)
        *(floatx4*)(orow + mi * 16 + quad * 4) = o_acc[mi];
}

// ---------------------------------------------------------------------------
// Merge the 3 segment-partials per (b,h,qt) + fused W_out fp32->bf16 convert.
// (verbatim from passing R12)
// ---------------------------------------------------------------------------
__global__ __launch_bounds__(256) void attn_combine(const float* __restrict__ pO_lo,
                                                    const float* __restrict__ pO_hi,
                                                    const float* __restrict__ pml,
                                                    u16* __restrict__ Ctx,
                                                    const float* __restrict__ woutf,
                                                    u16* __restrict__ wob) {
    const int g = blockIdx.x;            // b*256 + h*16 + qt
    const int qt = g & 15;
    const int h  = (g >> 4) & 15;
    const int b  = g >> 8;
    const int t  = threadIdx.x;
    const int q  = t >> 2;
    const int d0 = (t & 3) * 16;
    const int p0 = g * 3;

    // fused convert: one 8-elem chunk per thread (independent of main work)
    {
        const long long c = (long long)g * 256 + t;
        floatx4 x = *(const floatx4*)(woutf + c * 8);
        floatx4 y = *(const floatx4*)(woutf + c * 8 + 4);
        u16x8 o;
        #pragma unroll
        for (int j = 0; j < 4; j++) { o[j] = f2bf(x[j]); o[4 + j] = f2bf(y[j]); }
        *(u16x8*)(wob + c * 8) = o;
    }

    float m[3], l[3];
    #pragma unroll
    for (int s = 0; s < 3; s++) {
        m[s] = pml[(long long)(p0 + s) * 128 + q * 2];
        l[s] = pml[(long long)(p0 + s) * 128 + q * 2 + 1];
    }
    float M = fmaxf(m[0], fmaxf(m[1], m[2]));
    float w[3];
    #pragma unroll
    for (int s = 0; s < 3; s++) w[s] = exp2f(m[s] - M);
    float L = w[0] * l[0] + w[1] * l[1] + w[2] * l[2];
    float invL = 1.0f / L;

    const float* O[3];
    #pragma unroll
    for (int s = 0; s < 3; s++) {
        int pp = p0 + s;
        O[s] = ((pp < 512) ? (pO_lo + (long long)pp * 4096)
                           : (pO_hi + (long long)(pp - 512) * 4096))
               + (long long)q * 64 + d0;
    }

    long long crow = ((long long)(b * 1024 + qt * 64 + q)) * 1024 + h * 64 + d0;
    #pragma unroll
    for (int i = 0; i < 16; i += 4) {
        floatx4 a  = *(const floatx4*)(O[0] + i);
        floatx4 bb = *(const floatx4*)(O[1] + i);
        floatx4 cc = *(const floatx4*)(O[2] + i);
        #pragma unroll
        for (int j = 0; j < 4; j++)
            Ctx[crow + i + j] = f2bf((w[0] * a[j] + w[1] * bb[j] + w[2] * cc[j]) * invL);
    }
}

// ---------------------------------------------------------------------------
// residual + LayerNorm + mask; sums the FOUR split-K out-proj partials.
// (verbatim from passing R12)
// ---------------------------------------------------------------------------
__global__ __launch_bounds__(256) void ln_kernel(const float* __restrict__ AO,
                                                 const float* __restrict__ HQ,
                                                 const float* __restrict__ g,
                                                 const float* __restrict__ bb,
                                                 const float* __restrict__ mask,
                                                 float* __restrict__ Out) {
    const int row = blockIdx.x;
    const int t = threadIdx.x;
    const int base = row * 1024 + t * 4;
    floatx4 a0 = *(const floatx4*)&AO[base];
    floatx4 a1 = *(const floatx4*)&AO[base + 2097152];
    floatx4 a2 = *(const floatx4*)&AO[base + 2 * 2097152];
    floatx4 a3 = *(const floatx4*)&AO[base + 3 * 2097152];
    floatx4 hq = *(const floatx4*)&HQ[base];
    float x[4];
    #pragma unroll
    for (int i = 0; i < 4; i++) x[i] = (a0[i] + a1[i]) + (a2[i] + a3[i]) + hq[i];
    float s = x[0] + x[1] + x[2] + x[3];
    float ss = x[0]*x[0] + x[1]*x[1] + x[2]*x[2] + x[3]*x[3];
    #pragma unroll
    for (int off = 32; off >= 1; off >>= 1) { s += __shfl_xor(s, off); ss += __shfl_xor(ss, off); }
    __shared__ float smem[8];
    int wave = t >> 6, lane = t & 63;
    if (lane == 0) { smem[wave] = s; smem[4 + wave] = ss; }
    __syncthreads();
    s  = smem[0] + smem[1] + smem[2] + smem[3];
    ss = smem[4] + smem[5] + smem[6] + smem[7];
    float mu  = s * (1.f / 1024.f);
    float var = ss * (1.f / 1024.f) - mu * mu;
    float rs  = rsqrtf(var + 1e-5f);
    float mv  = mask[row];
    floatx4 g4 = *(const floatx4*)&g[t * 4];
    floatx4 b4 = *(const floatx4*)&bb[t * 4];
    floatx4 y4;
    #pragma unroll
    for (int i = 0; i < 4; i++) y4[i] = ((x[i] - mu) * rs * g4[i] + b4[i]) * mv;
    *(floatx4*)&Out[base] = y4;
}

// ---------------------------------------------------------------------------
// Workspace map (high-water 44.75 MB, unchanged from passing R12):
//   ws+0      q_b  4 MB  (-> ctx bf16 in place after combine)
//   ws+4 MB   k_b 12 MB  (dead after attn -> wob 2 MB at ws+4 [combine];
//                         ao0 8 MB at ws+8 [gemm_out])
//   ws+16 MB  vT  12 MB  (dead after attn -> ao1 8 MB at ws+16, ao2 at ws+24)
//   ws+28 MB  a_q+a_kv 16 MB (cvt->proj) -> pO_hi 16 MB (attn->combine)
//                         -> ao3 8 MB at ws+32 [gemm_out]
//   ws+44 MB  pml 0.75 MB
//   d_out 8 MB: wb bf16 6 MB (cvt->proj) -> pO_lo (attn->combine) -> output.
// ---------------------------------------------------------------------------
extern "C" void kernel_launch(void* const* d_in, const int* in_sizes, int n_in,
                              void* d_out, int out_size, void* d_ws, size_t ws_size,
                              hipStream_t stream) {
    (void)in_sizes; (void)n_in; (void)out_size; (void)ws_size;
    const float* h_q   = (const float*)d_in[0];
    const float* h_kv1 = (const float*)d_in[1];
    const float* h_kv2 = (const float*)d_in[2];
    const float* maskp = (const float*)d_in[3];
    const float* win   = (const float*)d_in[4];
    const float* binp  = (const float*)d_in[5];
    const float* wout  = (const float*)d_in[6];
    const float* bout  = (const float*)d_in[7];
    const float* ln_g  = (const float*)d_in[8];
    const float* ln_b  = (const float*)d_in[9];
    float* outp = (float*)d_out;

    char* ws = (char*)d_ws;
    const size_t MB = 1024 * 1024;
    u16*   q_b   = (u16*)(ws);
    u16*   k_b   = (u16*)(ws + 4 * MB);
    u16*   vT    = (u16*)(ws + 16 * MB);
    u16*   ctx_b = q_b;
    u16*   a_q   = (u16*)(ws + 28 * MB);
    u16*   a_kv  = (u16*)(ws + 32 * MB);
    u16*   wb    = (u16*)d_out;                // scratch until attn
    float* pO_lo = (float*)d_out;
    float* pO_hi = (float*)(ws + 28 * MB);
    u16*   wob   = (u16*)(ws + 4 * MB);        // after attn (dead k_b head)
    float* pml   = (float*)(ws + 44 * MB);
    float* ao    = (float*)(ws + 8 * MB);      // 4 partials, 8 MB apart (8..40)

    cvt_all<<<2048, 256, 0, stream>>>(h_q, h_kv1, h_kv2, win, a_q, a_kv, wb);
    gemm_proj<<<896, 256, 0, stream>>>(a_q, a_kv, wb, binp, q_b, k_b, vT);
    attn_seg<<<1536, 256, 0, stream>>>(q_b, k_b, vT, pO_lo, pO_hi, pml);
    attn_combine<<<512, 256, 0, stream>>>(pO_lo, pO_hi, pml, ctx_b, wout, wob);
    gemm_out<<<512, 256, 0, stream>>>(ctx_b, wob, bout, ao);
    ln_kernel<<<2048, 256, 0, stream>>>(ao, h_q, ln_g, ln_b, maskp, outp);
}

// Round 14
// 209.094 us; speedup vs baseline: 1.0413x; 1.0413x over previous
//
#include <hip/hip_runtime.h>
#include <stdint.h>

typedef unsigned short u16;
typedef unsigned int u32;
typedef __bf16 bf16x8 __attribute__((ext_vector_type(8)));
typedef float floatx4 __attribute__((ext_vector_type(4)));
typedef u16 u16x8 __attribute__((ext_vector_type(8)));
typedef u16 u16x4 __attribute__((ext_vector_type(4)));

__device__ __forceinline__ u16 f2bf(float f) {
    __bf16 h = (__bf16)f;
    return __builtin_bit_cast(u16, h);
}

// async global->LDS, 16B per lane. LDS dest = wave-uniform base + lane*16.
__device__ __forceinline__ void gll16(const u16* g, u16* l) {
    typedef __attribute__((address_space(1))) u32 gu32;
    typedef __attribute__((address_space(3))) u32 lu32;
    __builtin_amdgcn_global_load_lds((gu32*)g, (lu32*)l, 16, 0, 0);
}

// ---------------------------------------------------------------------------
// One-shot fp32->bf16 convert of h_q, concat(kv1,kv2), and W_in. (verbatim)
// ---------------------------------------------------------------------------
__global__ __launch_bounds__(256) void cvt_all(const float* __restrict__ hq,
                                               const float* __restrict__ kv1,
                                               const float* __restrict__ kv2,
                                               const float* __restrict__ win,
                                               u16* __restrict__ a_q,
                                               u16* __restrict__ a_kv,
                                               u16* __restrict__ wb) {
    const int NQ = 262144, NKV = 786432, NW = 393216;   // 8-elem chunks
    int i = blockIdx.x * 256 + threadIdx.x;
    const int stride = gridDim.x * 256;
    for (; i < NQ + NKV + NW; i += stride) {
        const float* src; u16* dst;
        if (i < NQ) {
            src = hq + (long long)i * 8; dst = a_q + (long long)i * 8;
        } else if (i < NQ + NKV) {
            int c = i - NQ;
            int row = c >> 7;                 // 128 chunks per 1024-elem row
            int col = (c & 127) * 8;
            int b = row >= 3072, r = row - b * 3072;
            src = (r < 1024) ? kv1 + ((long long)(b * 1024 + r)) * 1024 + col
                             : kv2 + ((long long)(b * 2048 + (r - 1024))) * 1024 + col;
            dst = a_kv + (long long)row * 1024 + col;
        } else {
            int c = i - (NQ + NKV);
            src = win + (long long)c * 8; dst = wb + (long long)c * 8;
        }
        floatx4 x = *(const floatx4*)src;
        floatx4 y = *(const floatx4*)(src + 4);
        u16x8 o;
        #pragma unroll
        for (int j = 0; j < 4; j++) { o[j] = f2bf(x[j]); o[4 + j] = f2bf(y[j]); }
        *(u16x8*)dst = o;
    }
}

// ---------------------------------------------------------------------------
// Fused Q+K+V projection (reverted to R12's best-measured variant): BK=64,
// 64 KB LDS, XOR swizzle, race-correct counted-vmcnt sync:
//   issue 8 glls(next) -> vmcnt(8) [own cur-tile loads landed]
//   -> s_barrier [propagates block-wide] -> ds_read+MFMA
//   -> lgkmcnt(0) -> s_barrier [WAR].
// Q pre-scaled by 0.125*log2(e); V written transposed vT[b][d][key].
// ---------------------------------------------------------------------------
__global__ __launch_bounds__(256) void gemm_proj(const u16* __restrict__ aq,
                                                 const u16* __restrict__ akv,
                                                 const u16* __restrict__ wb,
                                                 const float* __restrict__ bias,
                                                 u16* __restrict__ Qo,
                                                 u16* __restrict__ Ko,
                                                 u16* __restrict__ VTg) {
    __shared__ u16 lds[2][2][8192];            // [buf][A|B][128 rows x 64 cols]
    const int tid = threadIdx.x;
    const int wave = tid >> 6, lane = tid & 63;
    const int lane16 = lane & 15, quad = lane >> 4;
    const int bid = blockIdx.x;
    const int g = (bid & 7) * 112 + (bid >> 3);   // XCD swizzle, 896%8==0
    const bool qblk = g < 128;
    int my, nx;
    if (qblk) { my = g >> 3; nx = g & 7; }            // 16 x 8
    else { int gg = g - 128; my = gg >> 4; nx = gg & 15; }  // 48 x 16
    const int rowBase = my * 128;
    const int colBase = nx * 128;
    const int wrow = (qblk ? 0 : 1024) + colBase;
    const int wm = (wave >> 1) * 64, wn = (wave & 1) * 64;

    floatx4 acc[4][4];
    #pragma unroll
    for (int am = 0; am < 4; am++)
        #pragma unroll
        for (int bn = 0; bn < 4; bn++) acc[am][bn] = floatx4{0.f, 0.f, 0.f, 0.f};

    const int srow8 = tid >> 3;
    const int scol = ((tid & 7) ^ (srow8 & 7)) * 8;
    const u16* aS = (qblk ? aq : akv) + (long long)(rowBase + srow8) * 1024 + scol;
    const u16* bS = wb + (long long)(wrow + srow8) * 1024 + scol;
    u16* lbase = &lds[0][0][0];
    const int ldst = wave * 512;               // u16; HW adds lane*16 B

    const int cko0 = ((quad ^ (lane16 & 7)) * 8);        // k-half 0
    const int cko1 = (((4 + quad) ^ (lane16 & 7)) * 8);  // k-half 1

    {   // prologue: stage tile 0 into buf 0; full drain ONCE
        u16* dA = lbase; u16* dB = lbase + 8192;
        #pragma unroll
        for (int j = 0; j < 4; j++) {
            gll16(aS + j * 32768, dA + j * 2048 + ldst);
            gll16(bS + j * 32768, dB + j * 2048 + ldst);
        }
    }
    __syncthreads();

    int buf = 0;
    for (int t = 0; t < 16; t++) {
        if (t < 15) {                          // issue next tile FIRST
            const int k0 = (t + 1) * 64;
            u16* dA = lbase + (buf ^ 1) * 16384;
            u16* dB = dA + 8192;
            #pragma unroll
            for (int j = 0; j < 4; j++) {
                gll16(aS + j * 32768 + k0, dA + j * 2048 + ldst);
                gll16(bS + j * 32768 + k0, dB + j * 2048 + ldst);
            }
            asm volatile("s_waitcnt vmcnt(8)" ::: "memory");  // cur landed (own)
        } else {
            asm volatile("s_waitcnt vmcnt(0)" ::: "memory");
        }
        __builtin_amdgcn_s_barrier();          // DATA-READY: all waves landed
        __builtin_amdgcn_sched_barrier(0);
        const u16* Ab = lbase + buf * 16384;
        const u16* Bb = Ab + 8192;
        u16x8 a0[4], a1[4], b0[4], b1[4];
        #pragma unroll
        for (int i = 0; i < 4; i++) {
            a0[i] = *(const u16x8*)&Ab[(wm + i * 16 + lane16) * 64 + cko0];
            a1[i] = *(const u16x8*)&Ab[(wm + i * 16 + lane16) * 64 + cko1];
            b0[i] = *(const u16x8*)&Bb[(wn + i * 16 + lane16) * 64 + cko0];
            b1[i] = *(const u16x8*)&Bb[(wn + i * 16 + lane16) * 64 + cko1];
        }
        #pragma unroll
        for (int am = 0; am < 4; am++)
            #pragma unroll
            for (int bn = 0; bn < 4; bn++)
                acc[am][bn] = __builtin_amdgcn_mfma_f32_16x16x32_bf16(
                    __builtin_bit_cast(bf16x8, a0[am]),
                    __builtin_bit_cast(bf16x8, b0[bn]), acc[am][bn], 0, 0, 0);
        #pragma unroll
        for (int am = 0; am < 4; am++)
            #pragma unroll
            for (int bn = 0; bn < 4; bn++)
                acc[am][bn] = __builtin_amdgcn_mfma_f32_16x16x32_bf16(
                    __builtin_bit_cast(bf16x8, a1[am]),
                    __builtin_bit_cast(bf16x8, b1[bn]), acc[am][bn], 0, 0, 0);
        // WAR barrier only — next-tile glls stay in flight (no vmcnt drain)
        asm volatile("s_waitcnt lgkmcnt(0)" ::: "memory");
        __builtin_amdgcn_s_barrier();
        __builtin_amdgcn_sched_barrier(0);
        buf ^= 1;
    }

    const float* bcol = bias + (qblk ? 0 : 1024) + colBase;
    if (qblk || nx < 8) {                      // Q / K: natural [row][d] bf16
        u16* Cb = qblk ? Qo : Ko;
        #pragma unroll
        for (int am = 0; am < 4; am++)
            #pragma unroll
            for (int bn = 0; bn < 4; bn++)
                #pragma unroll
                for (int r = 0; r < 4; r++) {
                    int row = rowBase + wm + am * 16 + quad * 4 + r;
                    int col = wn + bn * 16 + lane16;
                    float v = acc[am][bn][r] + bcol[col];
                    if (qblk) v *= 0.1803368801f;   // 0.125*log2(e): exp2 domain
                    Cb[(long long)row * 1024 + colBase + col] = f2bf(v);
                }
    } else {                                   // V: transposed vT[b][d][key]
        const int b_ = rowBase >= 3072;
        const int keyBase = rowBase - b_ * 3072 + wm;
        #pragma unroll
        for (int am = 0; am < 4; am++)
            #pragma unroll
            for (int bn = 0; bn < 4; bn++) {
                int col = wn + bn * 16 + lane16;
                int d = colBase - 1024 + col;
                int key0 = keyBase + am * 16 + quad * 4;
                u16x4 pk;
                #pragma unroll
                for (int r = 0; r < 4; r++) pk[r] = f2bf(acc[am][bn][r] + bcol[col]);
                *(u16x4*)&VTg[((long long)(b_ * 1024 + d)) * 3072 + key0] = pk;
            }
    }
}

// ---------------------------------------------------------------------------
// Out-projection (verbatim from passing R12): split-K=4, BK=64, counted-vmcnt
// 2-barrier sync. fp32 partials ao[kh] (8 MB apart); ln sums all 4.
// ---------------------------------------------------------------------------
__global__ __launch_bounds__(256) void gemm_out(const u16* __restrict__ ctx,
                                                const u16* __restrict__ wob,
                                                const float* __restrict__ bias,
                                                float* __restrict__ ao) {
    __shared__ u16 lds[2][2][8192];
    const int tid = threadIdx.x;
    const int wave = tid >> 6, lane = tid & 63;
    const int lane16 = lane & 15, quad = lane >> 4;
    const int bid = blockIdx.x;
    const int g = (bid & 7) * 64 + (bid >> 3);        // 512%8==0
    const int my = g >> 5;                            // 16
    const int r5 = g & 31;
    const int nx = r5 >> 2;                           // 8
    const int kh = r5 & 3;                            // 4
    const int rowBase = my * 128, colBase = nx * 128, kbase = kh * 256;
    const int wm = (wave >> 1) * 64, wn = (wave & 1) * 64;

    floatx4 acc[4][4];
    #pragma unroll
    for (int am = 0; am < 4; am++)
        #pragma unroll
        for (int bn = 0; bn < 4; bn++) acc[am][bn] = floatx4{0.f, 0.f, 0.f, 0.f};

    const int srow8 = tid >> 3;
    const int scol = ((tid & 7) ^ (srow8 & 7)) * 8;
    const u16* aS = ctx + (long long)(rowBase + srow8) * 1024 + kbase + scol;
    const u16* bS = wob + (long long)(colBase + srow8) * 1024 + kbase + scol;
    u16* lbase = &lds[0][0][0];
    const int ldst = wave * 512;
    const int cko0 = ((quad ^ (lane16 & 7)) * 8);
    const int cko1 = (((4 + quad) ^ (lane16 & 7)) * 8);

    {
        u16* dA = lbase; u16* dB = lbase + 8192;
        #pragma unroll
        for (int j = 0; j < 4; j++) {
            gll16(aS + j * 32768, dA + j * 2048 + ldst);
            gll16(bS + j * 32768, dB + j * 2048 + ldst);
        }
    }
    __syncthreads();

    int buf = 0;
    for (int t = 0; t < 4; t++) {
        if (t < 3) {
            const int k0 = (t + 1) * 64;
            u16* dA = lbase + (buf ^ 1) * 16384;
            u16* dB = dA + 8192;
            #pragma unroll
            for (int j = 0; j < 4; j++) {
                gll16(aS + j * 32768 + k0, dA + j * 2048 + ldst);
                gll16(bS + j * 32768 + k0, dB + j * 2048 + ldst);
            }
            asm volatile("s_waitcnt vmcnt(8)" ::: "memory");
        } else {
            asm volatile("s_waitcnt vmcnt(0)" ::: "memory");
        }
        __builtin_amdgcn_s_barrier();          // DATA-READY barrier
        __builtin_amdgcn_sched_barrier(0);
        const u16* Ab = lbase + buf * 16384;
        const u16* Bb = Ab + 8192;
        u16x8 a0[4], a1[4], b0[4], b1[4];
        #pragma unroll
        for (int i = 0; i < 4; i++) {
            a0[i] = *(const u16x8*)&Ab[(wm + i * 16 + lane16) * 64 + cko0];
            a1[i] = *(const u16x8*)&Ab[(wm + i * 16 + lane16) * 64 + cko1];
            b0[i] = *(const u16x8*)&Bb[(wn + i * 16 + lane16) * 64 + cko0];
            b1[i] = *(const u16x8*)&Bb[(wn + i * 16 + lane16) * 64 + cko1];
        }
        #pragma unroll
        for (int am = 0; am < 4; am++)
            #pragma unroll
            for (int bn = 0; bn < 4; bn++)
                acc[am][bn] = __builtin_amdgcn_mfma_f32_16x16x32_bf16(
                    __builtin_bit_cast(bf16x8, a0[am]),
                    __builtin_bit_cast(bf16x8, b0[bn]), acc[am][bn], 0, 0, 0);
        #pragma unroll
        for (int am = 0; am < 4; am++)
            #pragma unroll
            for (int bn = 0; bn < 4; bn++)
                acc[am][bn] = __builtin_amdgcn_mfma_f32_16x16x32_bf16(
                    __builtin_bit_cast(bf16x8, a1[am]),
                    __builtin_bit_cast(bf16x8, b1[bn]), acc[am][bn], 0, 0, 0);
        asm volatile("s_waitcnt lgkmcnt(0)" ::: "memory");
        __builtin_amdgcn_s_barrier();          // WAR barrier
        __builtin_amdgcn_sched_barrier(0);
        buf ^= 1;
    }

    float* Co = ao + (long long)kh * 2097152;  // partials 8 MB (2M floats) apart
    #pragma unroll
    for (int am = 0; am < 4; am++)
        #pragma unroll
        for (int bn = 0; bn < 4; bn++)
            #pragma unroll
            for (int r = 0; r < 4; r++) {
                int row = rowBase + wm + am * 16 + quad * 4 + r;
                int col = colBase + wn + bn * 16 + lane16;
                float v = acc[am][bn][r] + (kh == 0 ? bias[col] : 0.f);
                Co[(long long)row * 1024 + col] = v;
            }
}

// ---------------------------------------------------------------------------
// MFMA flash attention v6 (verbatim from passing R12): race-fixed counted-
// vmcnt pipeline, longest-first dispatch, l via ones-MFMA, exp2, defer-max.
// ---------------------------------------------------------------------------
#define ATTN_TILE(DIAG_, HAVENEXT_)                                           \
{                                                                             \
    const int cur = t & 1;                                                    \
    if (HAVENEXT_) {                                                          \
        const long long ko = (long long)(t + 1) * 65536;                      \
        const long long vo = (long long)(t + 1) * 64;                         \
        _Pragma("unroll")                                                     \
        for (int j = 0; j < 2; j++) {                                         \
            gll16(kS + ko + j * 32768, &Kt[cur ^ 1][j * 2048 + ldst]);        \
            gll16(vS + vo + (long long)j * 32 * 3072, &Vt[cur ^ 1][j * 2048 + ldst]); \
        }                                                                     \
        asm volatile("s_waitcnt vmcnt(4)" ::: "memory");  /* own cur landed */ \
    } else {                                                                  \
        asm volatile("s_waitcnt vmcnt(0)" ::: "memory");                      \
    }                                                                         \
    __builtin_amdgcn_s_barrier();              /* DATA-READY: all waves */    \
    __builtin_amdgcn_sched_barrier(0);                                        \
    floatx4 sacc[4];                                                          \
    _Pragma("unroll")                                                         \
    for (int mi = 0; mi < 4; mi++) sacc[mi] = floatx4{0.f, 0.f, 0.f, 0.f};    \
    __builtin_amdgcn_s_setprio(1);                                            \
    _Pragma("unroll")                                                         \
    for (int mi = 0; mi < 4; mi++) {                                          \
        u16x8 kf = *(const u16x8*)&Kt[cur][(mi * 16 + lane16) * 64 + slot0];  \
        sacc[mi] = __builtin_amdgcn_mfma_f32_16x16x32_bf16(                   \
            __builtin_bit_cast(bf16x8, kf), qf[0], sacc[mi], 0, 0, 0);        \
    }                                                                         \
    _Pragma("unroll")                                                         \
    for (int mi = 0; mi < 4; mi++) {                                          \
        u16x8 kf = *(const u16x8*)&Kt[cur][(mi * 16 + lane16) * 64 + slot1];  \
        sacc[mi] = __builtin_amdgcn_mfma_f32_16x16x32_bf16(                   \
            __builtin_bit_cast(bf16x8, kf), qf[1], sacc[mi], 0, 0, 0);        \
    }                                                                         \
    __builtin_amdgcn_s_setprio(0);                                            \
    if (DIAG_) {                               /* mask only on diagonal tile */ \
        _Pragma("unroll")                                                     \
        for (int mi = 0; mi < 4; mi++)                                        \
            _Pragma("unroll")                                                 \
            for (int r = 0; r < 4; r++)                                       \
                if ((mi * 16 + quad * 4 + r) > qloc) sacc[mi][r] = -1e30f;    \
    }                                                                         \
    float tmax = fmaxf(sacc[0][0], sacc[0][1]);                               \
    tmax = fmaxf(tmax, fmaxf(sacc[0][2], sacc[0][3]));                        \
    _Pragma("unroll")                                                         \
    for (int mi = 1; mi < 4; mi++) {                                          \
        tmax = fmaxf(tmax, fmaxf(sacc[mi][0], sacc[mi][1]));                  \
        tmax = fmaxf(tmax, fmaxf(sacc[mi][2], sacc[mi][3]));                  \
    }                                                                         \
    if (!__all(tmax <= m_i + 8.0f)) {          /* rescale only on big jump */ \
        float tr = fmaxf(tmax, __shfl_xor(tmax, 16));                         \
        tr = fmaxf(tr, __shfl_xor(tr, 32));                                   \
        float m_new = fmaxf(m_i, tr);                                         \
        float alpha = exp2f(m_i - m_new);                                     \
        _Pragma("unroll")                                                     \
        for (int mi = 0; mi < 4; mi++)                                        \
            _Pragma("unroll")                                                 \
            for (int r = 0; r < 4; r++) o_acc[mi][r] *= alpha;                \
        l_acc[0] *= alpha;                     /* only [0] is ever read */    \
        m_i = m_new;                                                          \
    }                                                                         \
    _Pragma("unroll")                                                         \
    for (int mi = 0; mi < 4; mi++) {                                          \
        u16x4 pk;                                                             \
        _Pragma("unroll")                                                     \
        for (int r = 0; r < 4; r++) pk[r] = f2bf(exp2f(sacc[mi][r] - m_i));   \
        *(u16x4*)&Ps[wave][lane16 * 64 +                                      \
            (((mi * 2 + (quad >> 1)) ^ (lane16 & 7)) << 3) + (quad & 1) * 4] = pk; \
    }                                                                         \
    __builtin_amdgcn_wave_barrier();                                          \
    __builtin_amdgcn_s_setprio(1);                                            \
    _Pragma("unroll")                                                         \
    for (int c = 0; c < 2; c++) {                                             \
        bf16x8 pf = __builtin_bit_cast(bf16x8, *(const u16x8*)&Ps[wave][      \
            lane16 * 64 + (((c * 4 + quad) ^ (lane16 & 7)) << 3)]);           \
        const int slot = c ? slot1 : slot0;                                   \
        _Pragma("unroll")                                                     \
        for (int mi = 0; mi < 4; mi++) {                                      \
            bf16x8 vf = __builtin_bit_cast(bf16x8,                            \
                *(const u16x8*)&Vt[cur][(mi * 16 + lane16) * 64 + slot]);     \
            o_acc[mi] = __builtin_amdgcn_mfma_f32_16x16x32_bf16(vf, pf, o_acc[mi], 0, 0, 0); \
        }                                                                     \
        l_acc = __builtin_amdgcn_mfma_f32_16x16x32_bf16(onesf, pf, l_acc, 0, 0, 0); \
    }                                                                         \
    __builtin_amdgcn_s_setprio(0);                                            \
    if (HAVENEXT_) {                           /* WAR barrier, NO vmcnt drain */ \
        asm volatile("s_waitcnt lgkmcnt(0)" ::: "memory");                    \
        __builtin_amdgcn_s_barrier();                                         \
        __builtin_amdgcn_sched_barrier(0);                                    \
    }                                                                         \
}

__global__ __launch_bounds__(256) void attn_seg(const u16* __restrict__ Q,
                                                const u16* __restrict__ Kb,
                                                const u16* __restrict__ VTg,
                                                float* __restrict__ pO_lo,
                                                float* __restrict__ pO_hi,
                                                float* __restrict__ pml) {
    __shared__ u16 Kt[2][4096];        // [key 64][d 64], d-chunk XOR-swizzled
    __shared__ u16 Vt[2][4096];        // [d 64][key 64], key-chunk XOR-swizzled
    __shared__ u16 Ps[4][1024];        // per-wave P, stride 64, granule-XOR
    const int tid = threadIdx.x;
    const int wave = tid >> 6, lane = tid & 63;
    const int lane16 = lane & 15, quad = lane >> 4;
    const int bid = blockIdx.x;
    // longest-first: 96 blocks per qt class (2b x 16h x 3seg), qt descending
    const int qrank = bid / 96;                  // 0..15
    const int r_    = bid - qrank * 96;          // 0..95
    const int qt  = 15 - qrank;
    const int b   = r_ / 48;
    const int r2  = r_ - b * 48;
    const int seg = r2 >> 4;
    const int h   = r2 & 15;
    const int l0 = qt * 64;
    const int wq = wave * 16;
    const int qloc = wq + lane16;

    bf16x8 qf[2];
    {
        const u16* qrow = Q + ((long long)(b * 1024 + l0 + wq + lane16)) * 1024 + h * 64;
        qf[0] = __builtin_bit_cast(bf16x8, *(const u16x8*)(qrow + quad * 8));
        qf[1] = __builtin_bit_cast(bf16x8, *(const u16x8*)(qrow + 32 + quad * 8));
    }
    u16x8 onesu;
    #pragma unroll
    for (int j = 0; j < 8; j++) onesu[j] = 0x3F80;       // bf16 1.0
    const bf16x8 onesf = __builtin_bit_cast(bf16x8, onesu);

    const int srow = tid >> 3;                       // 0..31
    const int csw8 = ((tid & 7) ^ (srow & 7)) * 8;
    const long long bh = ((long long)b * 3072) * 1024 + h * 64;
    const u16* kS = Kb + bh + ((long long)(seg * 1024)) * 1024
                    + (long long)srow * 1024 + csw8;             // +t*65536
    const u16* vS = VTg + ((long long)(b * 1024 + h * 64 + srow)) * 3072
                    + seg * 1024 + csw8;                          // +t*64
    const int ldst = wave * 512;                     // u16; HW adds lane*16B

    {   // prologue: tile 0 -> buf 0; full drain ONCE (Q loads + stage)
        #pragma unroll
        for (int j = 0; j < 2; j++) {
            gll16(kS + j * 32768, &Kt[0][j * 2048 + ldst]);
            gll16(vS + (long long)j * 32 * 3072, &Vt[0][j * 2048 + ldst]);
        }
    }
    __syncthreads();

    const int slot0 = ((quad ^ (lane16 & 7)) * 8);
    const int slot1 = (((4 + quad) ^ (lane16 & 7)) * 8);

    float m_i = -1e30f;
    floatx4 o_acc[4];
    floatx4 l_acc = floatx4{0.f, 0.f, 0.f, 0.f};     // row-sum via ones-MFMA
    #pragma unroll
    for (int mi = 0; mi < 4; mi++) o_acc[mi] = floatx4{0.f, 0.f, 0.f, 0.f};

    for (int t = 0; t < qt; t++) ATTN_TILE(false, true)   // full tiles, no mask
    { int t = qt; ATTN_TILE(true, false) }                // diagonal tile

    const float l_i = l_acc[0];    // full key-sum for q=lane16 (rows identical)

    // ---- emit partials (m in log2 domain; combine uses exp2) ----
    const int p = ((b * 16 + h) * 16 + qt) * 3 + seg;     // 0..1535
    float* op = (p < 512) ? (pO_lo + (long long)p * 4096)
                          : (pO_hi + (long long)(p - 512) * 4096);
    if (quad == 0) {
        pml[(long long)p * 128 + (wq + lane16) * 2]     = m_i;
        pml[(long long)p * 128 + (wq + lane16) * 2 + 1] = l_i;
    }
    float* orow = op + (long long)(wq + lane16) * 64;
    #pragma unroll
    for (int mi = 0; mi < 4; mi++)
        *(floatx4*)(orow + mi * 16 + quad * 4) = o_acc[mi];
}

// ---------------------------------------------------------------------------
// Merge the 3 segment-partials per (b,h,qt) + fused W_out fp32->bf16 convert.
// (verbatim from passing R12)
// ---------------------------------------------------------------------------
__global__ __launch_bounds__(256) void attn_combine(const float* __restrict__ pO_lo,
                                                    const float* __restrict__ pO_hi,
                                                    const float* __restrict__ pml,
                                                    u16* __restrict__ Ctx,
                                                    const float* __restrict__ woutf,
                                                    u16* __restrict__ wob) {
    const int g = blockIdx.x;            // b*256 + h*16 + qt
    const int qt = g & 15;
    const int h  = (g >> 4) & 15;
    const int b  = g >> 8;
    const int t  = threadIdx.x;
    const int q  = t >> 2;
    const int d0 = (t & 3) * 16;
    const int p0 = g * 3;

    // fused convert: one 8-elem chunk per thread (independent of main work)
    {
        const long long c = (long long)g * 256 + t;
        floatx4 x = *(const floatx4*)(woutf + c * 8);
        floatx4 y = *(const floatx4*)(woutf + c * 8 + 4);
        u16x8 o;
        #pragma unroll
        for (int j = 0; j < 4; j++) { o[j] = f2bf(x[j]); o[4 + j] = f2bf(y[j]); }
        *(u16x8*)(wob + c * 8) = o;
    }

    float m[3], l[3];
    #pragma unroll
    for (int s = 0; s < 3; s++) {
        m[s] = pml[(long long)(p0 + s) * 128 + q * 2];
        l[s] = pml[(long long)(p0 + s) * 128 + q * 2 + 1];
    }
    float M = fmaxf(m[0], fmaxf(m[1], m[2]));
    float w[3];
    #pragma unroll
    for (int s = 0; s < 3; s++) w[s] = exp2f(m[s] - M);
    float L = w[0] * l[0] + w[1] * l[1] + w[2] * l[2];
    float invL = 1.0f / L;

    const float* O[3];
    #pragma unroll
    for (int s = 0; s < 3; s++) {
        int pp = p0 + s;
        O[s] = ((pp < 512) ? (pO_lo + (long long)pp * 4096)
                           : (pO_hi + (long long)(pp - 512) * 4096))
               + (long long)q * 64 + d0;
    }

    long long crow = ((long long)(b * 1024 + qt * 64 + q)) * 1024 + h * 64 + d0;
    #pragma unroll
    for (int i = 0; i < 16; i += 4) {
        floatx4 a  = *(const floatx4*)(O[0] + i);
        floatx4 bb = *(const floatx4*)(O[1] + i);
        floatx4 cc = *(const floatx4*)(O[2] + i);
        #pragma unroll
        for (int j = 0; j < 4; j++)
            Ctx[crow + i + j] = f2bf((w[0] * a[j] + w[1] * bb[j] + w[2] * cc[j]) * invL);
    }
}

// ---------------------------------------------------------------------------
// residual + LayerNorm + mask; sums the FOUR split-K out-proj partials.
// (verbatim from passing R12)
// ---------------------------------------------------------------------------
__global__ __launch_bounds__(256) void ln_kernel(const float* __restrict__ AO,
                                                 const float* __restrict__ HQ,
                                                 const float* __restrict__ g,
                                                 const float* __restrict__ bb,
                                                 const float* __restrict__ mask,
                                                 float* __restrict__ Out) {
    const int row = blockIdx.x;
    const int t = threadIdx.x;
    const int base = row * 1024 + t * 4;
    floatx4 a0 = *(const floatx4*)&AO[base];
    floatx4 a1 = *(const floatx4*)&AO[base + 2097152];
    floatx4 a2 = *(const floatx4*)&AO[base + 2 * 2097152];
    floatx4 a3 = *(const floatx4*)&AO[base + 3 * 2097152];
    floatx4 hq = *(const floatx4*)&HQ[base];
    float x[4];
    #pragma unroll
    for (int i = 0; i < 4; i++) x[i] = (a0[i] + a1[i]) + (a2[i] + a3[i]) + hq[i];
    float s = x[0] + x[1] + x[2] + x[3];
    float ss = x[0]*x[0] + x[1]*x[1] + x[2]*x[2] + x[3]*x[3];
    #pragma unroll
    for (int off = 32; off >= 1; off >>= 1) { s += __shfl_xor(s, off); ss += __shfl_xor(ss, off); }
    __shared__ float smem[8];
    int wave = t >> 6, lane = t & 63;
    if (lane == 0) { smem[wave] = s; smem[4 + wave] = ss; }
    __syncthreads();
    s  = smem[0] + smem[1] + smem[2] + smem[3];
    ss = smem[4] + smem[5] + smem[6] + smem[7];
    float mu  = s * (1.f / 1024.f);
    float var = ss * (1.f / 1024.f) - mu * mu;
    float rs  = rsqrtf(var + 1e-5f);
    float mv  = mask[row];
    floatx4 g4 = *(const floatx4*)&g[t * 4];
    floatx4 b4 = *(const floatx4*)&bb[t * 4];
    floatx4 y4;
    #pragma unroll
    for (int i = 0; i < 4; i++) y4[i] = ((x[i] - mu) * rs * g4[i] + b4[i]) * mv;
    *(floatx4*)&Out[base] = y4;
}

// ---------------------------------------------------------------------------
// Workspace map (high-water 44.75 MB, unchanged from passing R12):
//   ws+0      q_b  4 MB  (-> ctx bf16 in place after combine)
//   ws+4 MB   k_b 12 MB  (dead after attn -> wob 2 MB at ws+4 [combine];
//                         ao0 8 MB at ws+8 [gemm_out])
//   ws+16 MB  vT  12 MB  (dead after attn -> ao1 8 MB at ws+16, ao2 at ws+24)
//   ws+28 MB  a_q+a_kv 16 MB (cvt->proj) -> pO_hi 16 MB (attn->combine)
//                         -> ao3 8 MB at ws+32 [gemm_out]
//   ws+44 MB  pml 0.75 MB
//   d_out 8 MB: wb bf16 6 MB (cvt->proj) -> pO_lo (attn->combine) -> output.
// ---------------------------------------------------------------------------
extern "C" void kernel_launch(void* const* d_in, const int* in_sizes, int n_in,
                              void* d_out, int out_size, void* d_ws, size_t ws_size,
                              hipStream_t stream) {
    (void)in_sizes; (void)n_in; (void)out_size; (void)ws_size;
    const float* h_q   = (const float*)d_in[0];
    const float* h_kv1 = (const float*)d_in[1];
    const float* h_kv2 = (const float*)d_in[2];
    const float* maskp = (const float*)d_in[3];
    const float* win   = (const float*)d_in[4];
    const float* binp  = (const float*)d_in[5];
    const float* wout  = (const float*)d_in[6];
    const float* bout  = (const float*)d_in[7];
    const float* ln_g  = (const float*)d_in[8];
    const float* ln_b  = (const float*)d_in[9];
    float* outp = (float*)d_out;

    char* ws = (char*)d_ws;
    const size_t MB = 1024 * 1024;
    u16*   q_b   = (u16*)(ws);
    u16*   k_b   = (u16*)(ws + 4 * MB);
    u16*   vT    = (u16*)(ws + 16 * MB);
    u16*   ctx_b = q_b;
    u16*   a_q   = (u16*)(ws + 28 * MB);
    u16*   a_kv  = (u16*)(ws + 32 * MB);
    u16*   wb    = (u16*)d_out;                // scratch until attn
    float* pO_lo = (float*)d_out;
    float* pO_hi = (float*)(ws + 28 * MB);
    u16*   wob   = (u16*)(ws + 4 * MB);        // after attn (dead k_b head)
    float* pml   = (float*)(ws + 44 * MB);
    float* ao    = (float*)(ws + 8 * MB);      // 4 partials, 8 MB apart (8..40)

    cvt_all<<<2048, 256, 0, stream>>>(h_q, h_kv1, h_kv2, win, a_q, a_kv, wb);
    gemm_proj<<<896, 256, 0, stream>>>(a_q, a_kv, wb, binp, q_b, k_b, vT);
    attn_seg<<<1536, 256, 0, stream>>>(q_b, k_b, vT, pO_lo, pO_hi, pml);
    attn_combine<<<512, 256, 0, stream>>>(pO_lo, pO_hi, pml, ctx_b, wout, wob);
    gemm_out<<<512, 256, 0, stream>>>(ctx_b, wob, bout, ao);
    ln_kernel<<<2048, 256, 0, stream>>>(ao, h_q, ln_g, ln_b, maskp, outp);
}